// Round 1
// 167.543 us; speedup vs baseline: 1.0630x; 1.0630x over previous
//
#include <hip/hip_runtime.h>
#include <hip/hip_bf16.h>

// Problem constants
#define BB 8
#define SS 2048
#define DD 1024
#define OO 1024
#define MM (BB * SS)   // 16384
#define KK DD          // 1024
#define NN OO          // 1024
#define CC 64          // chunks
#define LL 32          // chunk length (CC*LL == SS)

typedef __bf16 bf16x8 __attribute__((ext_vector_type(8)));
typedef __bf16 bf16x4 __attribute__((ext_vector_type(4)));
typedef float floatx4 __attribute__((ext_vector_type(4)));

__device__ __forceinline__ float4 fma4(float4 h, float4 a, float4 v) {
    h.x = fmaf(h.x, a.x, v.x);
    h.y = fmaf(h.y, a.y, v.y);
    h.z = fmaf(h.z, a.z, v.z);
    h.w = fmaf(h.w, a.w, v.w);
    return h;
}

// ---------------- Kernel 1: fused per-chunk carries + BC transpose/cast ----------------
__global__ __launch_bounds__(256) void prep(const float* __restrict__ x,
                                            const float* __restrict__ A,
                                            float* __restrict__ carry,
                                            const float* __restrict__ BC,
                                            __bf16* __restrict__ BCt) {
    __shared__ float tile[32][33];
    const int id = blockIdx.x;
    if (id < BB * CC) {
        const int c = id & (CC - 1);
        const int b = id >> 6;          // id / CC
        const int i4 = threadIdx.x;     // float4 index over D (0..255)
        const float4 a = ((const float4*)A)[i4];
        const float4* xp = (const float4*)(x + ((size_t)b * SS + (size_t)c * LL) * DD) + i4;
        float4 h = make_float4(0.f, 0.f, 0.f, 0.f);
#pragma unroll
        for (int t0 = 0; t0 < LL; t0 += 8) {
            float4 v[8];
#pragma unroll
            for (int u = 0; u < 8; ++u) v[u] = xp[(size_t)(t0 + u) * (DD / 4)];
#pragma unroll
            for (int u = 0; u < 8; ++u) h = fma4(h, a, v[u]);
        }
        ((float4*)carry)[((size_t)b * CC + c) * (DD / 4) + i4] = h;
    } else {
        const int t = id - BB * CC;
        const int o0 = (t & 31) * 32;
        const int d0 = (t >> 5) * 32;
        const int tx = threadIdx.x & 31;
        const int ty = threadIdx.x >> 5;   // 0..7
#pragma unroll
        for (int i = 0; i < 4; ++i) {
            const int dd = ty + i * 8;
            tile[dd][tx] = BC[(size_t)(d0 + dd) * OO + o0 + tx];
        }
        __syncthreads();
#pragma unroll
        for (int i = 0; i < 4; ++i) {
            const int oo = ty + i * 8;
            BCt[(size_t)(o0 + oo) * DD + d0 + tx] = (__bf16)tile[tx][oo];
        }
    }
}

// ---------------- Kernel 2: emit hs (bf16), chunk prefix computed in-kernel ----------------
__global__ __launch_bounds__(256) void scan_emit(const float* __restrict__ x,
                                                 const float* __restrict__ A,
                                                 const float* __restrict__ carry,
                                                 __bf16* __restrict__ hs) {
    const int id = blockIdx.x;
    const int c = id & (CC - 1);
    const int b = id >> 6;
    const int i4 = threadIdx.x;
    const float4 a = ((const float4*)A)[i4];
    float4 aL = a;
#pragma unroll
    for (int i = 0; i < 5; ++i) { aL.x *= aL.x; aL.y *= aL.y; aL.z *= aL.z; aL.w *= aL.w; }
    float4 h = make_float4(0.f, 0.f, 0.f, 0.f);
    const float4* cp = (const float4*)carry + (size_t)b * CC * (DD / 4) + i4;
    for (int j = 0; j < c; ++j) {
        const float4 cv = cp[(size_t)j * (DD / 4)];
        h.x = fmaf(h.x, aL.x, cv.x);
        h.y = fmaf(h.y, aL.y, cv.y);
        h.z = fmaf(h.z, aL.z, cv.z);
        h.w = fmaf(h.w, aL.w, cv.w);
    }
    const size_t base = ((size_t)b * SS + (size_t)c * LL) * DD;
    const float4* xp = (const float4*)(x + base) + i4;
    bf16x4* hp = (bf16x4*)(hs + base) + i4;
#pragma unroll
    for (int t0 = 0; t0 < LL; t0 += 8) {
        float4 v[8];
#pragma unroll
        for (int u = 0; u < 8; ++u) v[u] = xp[(size_t)(t0 + u) * (DD / 4)];
#pragma unroll
        for (int u = 0; u < 8; ++u) {
            h = fma4(h, a, v[u]);
            bf16x4 o;
            o[0] = (__bf16)h.x; o[1] = (__bf16)h.y; o[2] = (__bf16)h.z; o[3] = (__bf16)h.w;
            hp[(size_t)(t0 + u) * (DD / 4)] = o;
        }
    }
}

// ---------------- GEMM: C[m,n] = sum_k A[m,k] * Bt[n,k] ----------------
// 256x256 tile, BK=64, 8 waves (2 M x 4 N), each wave owns a 128x64 output.
// Counted-vmcnt pipeline (T3/T4): raw s_barrier (no vmcnt(0) drain in the
// main loop); stage(t+1) issued at iteration top; s_waitcnt vmcnt(8) keeps
// the next tile's 8 loads in flight across both barriers. Race-free:
//  - buffer buf[(t+1)&1] was last read at iteration t-1, whose closing
//    barrier precedes the stage issue (program order + asm memory fences);
//  - tile t's loads are vmcnt-complete + barrier-published before its
//    ds_reads.
// LDS swizzle for 128B row stride: chunk (r,q) stored at q^(r&7). Per
// 16-lane read phase: bank0 = 4*(q^(lanelo&7)) -> 8 bank-quads x 2 lanes
// = 2-way = free (m136). global_load_lds dest stays lane-linear; the
// permutation is applied to the global source (both-sides rule).
#define GTM 256
#define GTN 256
#define GTK 64
#define GNT (KK / GTK)   // 16

__device__ __forceinline__ void async16(void* lds, const void* g) {
    __builtin_amdgcn_global_load_lds(
        (__attribute__((address_space(1))) void*)(void*)g,
        (__attribute__((address_space(3))) void*)lds, 16, 0, 0);
}

#define MEMFENCE asm volatile("" ::: "memory")
#define BARRIER do { MEMFENCE; __builtin_amdgcn_s_barrier(); MEMFENCE; } while (0)

__global__ __launch_bounds__(512, 2) void gemm_bt(const __bf16* __restrict__ Am,
                                                  const __bf16* __restrict__ Bt,
                                                  float* __restrict__ C) {
    __shared__ __align__(16) __bf16 As[2][GTM * GTK];   // 2 x 32 KB
    __shared__ __align__(16) __bf16 Bs[2][GTN * GTK];   // 2 x 32 KB

    const int tid = threadIdx.x;          // 0..511
    const int wave = tid >> 6;            // 0..7
    const int lane = tid & 63;
    const int wm = (wave >> 2) * 128;     // 0 / 128
    const int wn = (wave & 3) * 64;       // 0,64,128,192
    const int lanelo = lane & 15;
    const int quad = lane >> 4;

    // XCD-chunked swizzle: 256 blocks = 8 XCDs x 32; the 4 blocks sharing an
    // A-panel (same mi, ni=0..3) land on one XCD -> A re-reads are L2 hits.
    const int bid = blockIdx.x;
    const int xcd = bid & 7;
    const int loc = bid >> 3;             // 0..31
    const int tile_m = (xcd * 8 + (loc >> 2)) * GTM;
    const int tile_n = (loc & 3) * GTN;

    // staging: 2048 16B-chunks per matrix per K-tile, 512 threads -> 4 each.
    // chunk cid: row r = cid>>3, LDS k-slot qs = cid&7 holds global k-group
    // qg = qs ^ (r&7).
    const __bf16* Abp[4];
    const __bf16* Bbp[4];
#pragma unroll
    for (int j = 0; j < 4; ++j) {
        const int cid = tid + j * 512;
        const int r = cid >> 3;
        const int qg = ((cid & 7) ^ (r & 7)) * 8;
        Abp[j] = Am + (size_t)(tile_m + r) * KK + qg;
        Bbp[j] = Bt + (size_t)(tile_n + r) * KK + qg;
    }

    floatx4 acc[8][4];
#pragma unroll
    for (int i = 0; i < 8; ++i)
#pragma unroll
        for (int j = 0; j < 4; ++j) acc[i][j] = (floatx4){0.f, 0.f, 0.f, 0.f};

    auto stage = [&](int t, int u) {
        const int k = t * GTK;
#pragma unroll
        for (int j = 0; j < 4; ++j)
            async16(&As[u][(tid + j * 512) * 8], Abp[j] + k);
#pragma unroll
        for (int j = 0; j < 4; ++j)
            async16(&Bs[u][(tid + j * 512) * 8], Bbp[j] + k);
    };

    auto compute = [&](int u) {
        const __bf16* as = As[u];
        const __bf16* bs = Bs[u];
#pragma unroll
        for (int kk = 0; kk < 2; ++kk) {
            bf16x8 af[8], bv[4];
#pragma unroll
            for (int ii = 0; ii < 8; ++ii) {
                const int row = wm + ii * 16 + lanelo;
                af[ii] = *(const bf16x8*)(as + row * GTK + ((((kk << 2) | quad) ^ (lanelo & 7)) * 8));
            }
#pragma unroll
            for (int j = 0; j < 4; ++j) {
                const int row = wn + j * 16 + lanelo;
                bv[j] = *(const bf16x8*)(bs + row * GTK + ((((kk << 2) | quad) ^ (lanelo & 7)) * 8));
            }
            __builtin_amdgcn_s_setprio(1);
#pragma unroll
            for (int ii = 0; ii < 8; ++ii)
#pragma unroll
                for (int j = 0; j < 4; ++j)
                    acc[ii][j] = __builtin_amdgcn_mfma_f32_16x16x32_bf16(af[ii], bv[j], acc[ii][j], 0, 0, 0);
            __builtin_amdgcn_s_setprio(0);
        }
    };

    // prologue: tile 0 -> buf 0 (8 loads in flight)
    stage(0, 0);

    for (int t = 0; t < GNT - 1; ++t) {
        stage(t + 1, (t + 1) & 1);                      // 16 in flight
        asm volatile("s_waitcnt vmcnt(8)" ::: "memory"); // tile t landed
        BARRIER;                                        // ...in every wave
        compute(t & 1);
        BARRIER;                                        // buf[t&1] free for t+2's stage
    }
    asm volatile("s_waitcnt vmcnt(0)" ::: "memory");
    BARRIER;
    compute((GNT - 1) & 1);

    // epilogue: row = quad*4 + r, col = lanelo
#pragma unroll
    for (int i = 0; i < 8; ++i) {
        const int row = tile_m + wm + i * 16 + quad * 4;
#pragma unroll
        for (int r = 0; r < 4; ++r) {
            float* crow = C + (size_t)(row + r) * NN + tile_n + wn + lanelo;
#pragma unroll
            for (int j = 0; j < 4; ++j) crow[j * 16] = acc[i][j][r];
        }
    }
}

extern "C" void kernel_launch(void* const* d_in, const int* in_sizes, int n_in,
                              void* d_out, int out_size, void* d_ws, size_t ws_size,
                              hipStream_t stream) {
    const float* x  = (const float*)d_in[0];   // [B,S,D]
    const float* A  = (const float*)d_in[1];   // [D]
    const float* BC = (const float*)d_in[2];   // [D,O]
    float* out = (float*)d_out;                // [B,S,O]

    char* ws = (char*)d_ws;
    __bf16* hs   = (__bf16*)ws;                                  // 33,554,432 B
    float* carry = (float*)(ws + 33554432);                      // 2 MB (BB*CC*DD*4)
    __bf16* BCt  = (__bf16*)(ws + 33554432 + 2097152);           // 2 MB

    prep<<<dim3(BB * CC + 1024), 256, 0, stream>>>(x, A, carry, BC, BCt);
    scan_emit<<<dim3(BB * CC), 256, 0, stream>>>(x, A, carry, hs);
    gemm_bt<<<dim3(256), 512, 0, stream>>>(hs, BCt, out);
}